// Round 3
// baseline (72499.463 us; speedup 1.0000x reference)
//
#include <hip/hip_runtime.h>
#include <hip/hip_bf16.h>

typedef unsigned short u16;
typedef unsigned int u32;
typedef short short8 __attribute__((ext_vector_type(8)));
typedef float floatx4 __attribute__((ext_vector_type(4)));

#define SLEN 2048
#define BATCH 64
#define FDIM 512
#define HDIM 512
#define NWG 128            // each WG owns 4 h-columns
#define NTH 256            // 4 waves
#define HBUF_U32 (BATCH*HDIM/2)    // 16384 u32 per h buffer
#define WS_BYTES (8192 + 2*HBUF_U32*4)

// fp32 -> bf16 round-to-nearest-even
__device__ __forceinline__ u16 f2bf_rne(float f) {
  union { float f; u32 u; } v; v.f = f;
  u32 u = v.u + 0x7FFFu + ((v.u >> 16) & 1u);
  return (u16)(u >> 16);
}
__device__ __forceinline__ float sigmoidf_fast(float x) {
  return 1.0f / (1.0f + __expf(-x));
}
__device__ __forceinline__ float tanhf_fast(float x) {
  return 1.0f - 2.0f / (__expf(2.0f * x) + 1.0f);
}

// Persistent LSTM. WG blk owns h-columns [4*blk, 4*blk+4).
// Gate-column order within the WG's 16 MFMA output columns: n = gate*4 + hc,
// gate 0..3 = i, f, g, o.
__global__ __launch_bounds__(NTH, 1)
void lstm_persistent(
    const float* __restrict__ x,
    const float* __restrict__ w_ii, const float* __restrict__ b_ii,
    const float* __restrict__ w_hi, const float* __restrict__ b_hi,
    const float* __restrict__ w_if, const float* __restrict__ b_if,
    const float* __restrict__ w_hf, const float* __restrict__ b_hf,
    const float* __restrict__ w_ig, const float* __restrict__ b_ig,
    const float* __restrict__ w_hg, const float* __restrict__ b_hg,
    const float* __restrict__ w_io, const float* __restrict__ b_io,
    const float* __restrict__ w_ho, const float* __restrict__ b_ho,
    float* __restrict__ out, u32* __restrict__ ctr, u32* __restrict__ hbuf)
{
  // Weights (fp32 -> bf16) in MFMA B-fragment order:
  // lds[(kk*64 + lane)*8 + j] = W[kk*32 + (lane>>4)*8 + j][4*blk + (n&3)], n=lane&15
  __shared__ u16 lds_wh[16 * 64 * 8];   // 16 KiB
  __shared__ u16 lds_wx[16 * 64 * 8];   // 16 KiB
  __shared__ float scratch[BATCH][17];  // C tile, padded
  __shared__ u16 hstage[BATCH][4];      // bf16 h staging for packed stores

  const int tid = threadIdx.x;
  const int blk = blockIdx.x;

  {
    const float* wh[4]  = {w_hi, w_hf, w_hg, w_ho};
    const float* wxp[4] = {w_ii, w_if, w_ig, w_io};
    for (int idx = tid; idx < 16 * 64 * 8; idx += NTH) {
      int j  = idx & 7;
      int L  = (idx >> 3) & 63;
      int kk = idx >> 9;
      int k  = kk * 32 + ((L >> 4) << 3) + j;
      int n  = L & 15;
      int g  = n >> 2, hc = n & 3;
      int col = blk * 4 + hc;
      lds_wh[idx] = f2bf_rne(wh[g][k * HDIM + col]);
      lds_wx[idx] = f2bf_rne(wxp[g][k * HDIM + col]);
    }
  }

  const int pb   = tid & 63;   // batch
  const int phc  = tid >> 6;   // 0..3 local h-col
  const int pcol = blk * 4 + phc;
  float bias[4];
  bias[0] = b_ii[pcol] + b_hi[pcol];
  bias[1] = b_if[pcol] + b_hf[pcol];
  bias[2] = b_ig[pcol] + b_hg[pcol];
  bias[3] = b_io[pcol] + b_ho[pcol];
  float c_reg = 0.0f;

  // MFMA A-fragment: m = lane&15, k = (lane>>4)*8 + j
  const int wave = tid >> 6;
  const int lane = tid & 63;
  const int am   = (wave << 4) + (lane & 15);
  const int ak0  = (lane >> 4) << 3;
  const float* xbase = x + (size_t)am * (SLEN * FDIM);

  __syncthreads();

  for (int t = 0; t < SLEN; ++t) {
    if (t > 0) {
      if (tid == 0) {
        while (__hip_atomic_load(&ctr[t - 1], __ATOMIC_ACQUIRE,
                                 __HIP_MEMORY_SCOPE_AGENT) < NWG) {
          __builtin_amdgcn_s_sleep(2);
        }
      }
      __syncthreads();
      __threadfence();   // extend acquire to all threads before h loads
    }

    const u32* hrow = hbuf + (t & 1) * HBUF_U32 + am * (HDIM / 2);
    const float* xrow = xbase + (size_t)t * FDIM;
    floatx4 acc = {0.f, 0.f, 0.f, 0.f};
#pragma unroll
    for (int kk = 0; kk < 16; ++kk) {
      union { u32 u[4]; short8 s; } ha;
      const int jd = kk * 16 + ((lane >> 4) << 2);
#pragma unroll
      for (int j = 0; j < 4; ++j)
        ha.u[j] = __hip_atomic_load(&hrow[jd + j], __ATOMIC_RELAXED,
                                    __HIP_MEMORY_SCOPE_AGENT);
      short8 bh = *(const short8*)(&lds_wh[(kk * 64 + lane) * 8]);
      acc = __builtin_amdgcn_mfma_f32_16x16x32_bf16(ha.s, bh, acc, 0, 0, 0);

      floatx4 xa = *(const floatx4*)(xrow + kk * 32 + ak0);
      floatx4 xb = *(const floatx4*)(xrow + kk * 32 + ak0 + 4);
      short8 ax;
#pragma unroll
      for (int j = 0; j < 4; ++j) {
        ax[j]     = (short)f2bf_rne(xa[j]);
        ax[4 + j] = (short)f2bf_rne(xb[j]);
      }
      short8 bx = *(const short8*)(&lds_wx[(kk * 64 + lane) * 8]);
      acc = __builtin_amdgcn_mfma_f32_16x16x32_bf16(ax, bx, acc, 0, 0, 0);
    }

    // C/D layout: col = lane&15, row = (lane>>4)*4 + reg
    {
      const int r0 = (wave << 4) + ((lane >> 4) << 2);
      const int cc = lane & 15;
#pragma unroll
      for (int r = 0; r < 4; ++r) scratch[r0 + r][cc] = acc[r];
    }
    __syncthreads();

    float pi = scratch[pb][0  + phc] + bias[0];
    float pf = scratch[pb][4  + phc] + bias[1];
    float pg = scratch[pb][8  + phc] + bias[2];
    float po = scratch[pb][12 + phc] + bias[3];
    float gi = sigmoidf_fast(pi);
    float gf = sigmoidf_fast(pf);
    float gg = tanhf_fast(pg);
    float go = sigmoidf_fast(po);
    c_reg = gf * c_reg + gi * gg;
    float h_new = go * tanhf_fast(c_reg);

    if (t == SLEN - 1) {
      out[pb * HDIM + pcol]                = h_new;   // fp32 output: h
      out[BATCH * HDIM + pb * HDIM + pcol] = c_reg;   // fp32 output: c
    } else {
      hstage[pb][phc] = f2bf_rne(h_new);
      __syncthreads();
      if (tid < 128) {
        const int pu = tid >> 6;   // 0..1: u32 column pair within our 4 cols
        u32 val = ((u32)hstage[pb][2 * pu + 1] << 16) | (u32)hstage[pb][2 * pu];
        __hip_atomic_store(
            &hbuf[((t + 1) & 1) * HBUF_U32 + pb * (HDIM / 2) + blk * 2 + pu],
            val, __ATOMIC_RELEASE, __HIP_MEMORY_SCOPE_AGENT);
      }
      __syncthreads();   // all packed stores issued before the arrival add
      __threadfence();
      if (tid == 0) {
        __hip_atomic_fetch_add(&ctr[t], 1u, __ATOMIC_RELEASE,
                               __HIP_MEMORY_SCOPE_AGENT);
      }
    }
  }
}

extern "C" void kernel_launch(void* const* d_in, const int* in_sizes, int n_in,
                              void* d_out, int out_size, void* d_ws, size_t ws_size,
                              hipStream_t stream) {
  // ws: [0,8192) arrival counters ctr[2048]; [8192, +128KiB) h double buffer (u32-packed bf16)
  u32* ctr  = (u32*)d_ws;
  u32* hbuf = (u32*)((char*)d_ws + 8192);
  (void)hipMemsetAsync(d_ws, 0, WS_BYTES, stream);  // zero counters + h0

  lstm_persistent<<<dim3(NWG), dim3(NTH), 0, stream>>>(
      (const float*)d_in[0],
      (const float*)d_in[1],  (const float*)d_in[2],   // w_ii, b_ii
      (const float*)d_in[3],  (const float*)d_in[4],   // w_hi, b_hi
      (const float*)d_in[5],  (const float*)d_in[6],   // w_if_, b_if_
      (const float*)d_in[7],  (const float*)d_in[8],   // w_hf, b_hf
      (const float*)d_in[9],  (const float*)d_in[10],  // w_ig, b_ig
      (const float*)d_in[11], (const float*)d_in[12],  // w_hg, b_hg
      (const float*)d_in[13], (const float*)d_in[14],  // w_io, b_io
      (const float*)d_in[15], (const float*)d_in[16],  // w_ho, b_ho
      (float*)d_out, ctr, hbuf);
}